// Round 22
// baseline (153.168 us; speedup 1.0000x reference)
//
#include <hip/hip_runtime.h>
#include <hip/hip_fp16.h>

#define BB 16384
#define NN 20
#define DD 64
#define IMGK 2048

using bf16x8 = __attribute__((ext_vector_type(8))) short;
using f32x4  = __attribute__((ext_vector_type(4))) float;

typedef __attribute__((address_space(1))) const unsigned int GUint;
typedef __attribute__((address_space(3))) unsigned int LUint;
__device__ __forceinline__ void gl_lds16(const void* g, void* l) {
  __builtin_amdgcn_global_load_lds((GUint*)g, (LUint*)l, 16, 0, 0);
}

__device__ __forceinline__ float waveReduceSum(float x) {
#pragma unroll
  for (int off = 32; off > 0; off >>= 1) x += __shfl_xor(x, off, 64);
  return x;
}

__device__ __forceinline__ float fast_tanh(float x) {
  float e = __expf(2.f * x);
  return 1.f - __fdividef(2.f, e + 1.f);
}

__device__ __forceinline__ short f2bf(float f) {
  union { float f; unsigned u; } c; c.f = f;
  unsigned r = c.u + 0x7fffu + ((c.u >> 16) & 1u);
  return (short)(r >> 16);
}
__device__ __forceinline__ float bf2f(short s) {
  union { unsigned u; float f; } c; c.u = ((unsigned)(unsigned short)s) << 16;
  return c.f;
}
// truncation bf16 (1 VALU op) — non-critical paths
__device__ __forceinline__ short f2bf_t(float f) {
  return (short)(__float_as_uint(f) >> 16);
}

// truncation pack: top 16 bits of (a,b) -> one u32. Pure VALU.
__device__ __forceinline__ unsigned pack_hi(float a, float b) {
  unsigned ua = __float_as_uint(a), ub = __float_as_uint(b);
  return (ub & 0xffff0000u) | (ua >> 16);
}
__device__ __forceinline__ float trunc_bf(float a) {
  return __uint_as_float(__float_as_uint(a) & 0xffff0000u);
}

// ---------------- prep: Wf (img, frag-ordered hi/lo, kq=32) + W1f (K=192) + Wcf (K=128) ----------------
__global__ __launch_bounds__(256)
void prep_kernel(const float* __restrict__ Wimg, const float* __restrict__ W1,
                 const float* __restrict__ Wc,
                 short* __restrict__ Wf, short* __restrict__ W1f,
                 short* __restrict__ Wcf) {
  int i = blockIdx.x * 256 + threadIdx.x;
  if (i < 32768) {
    const int lane = i & 63;
    const int h = (i >> 6) & 1;
    const int tt = (i >> 7) & 3;
    const int ks = (i >> 9) & 1;
    const int kq = i >> 10;
    const int n = 16 * tt + (lane & 15);
    const int kb = kq * 64 + ks * 32 + (lane >> 4) * 8;
    union { short s[8]; bf16x8 v; } o;
#pragma unroll
    for (int j = 0; j < 8; ++j) {
      float f = Wimg[(size_t)(kb + j) * 64 + n];
      short hi = f2bf(f);
      o.s[j] = h == 0 ? hi : f2bf(f - bf2f(hi));
    }
    reinterpret_cast<bf16x8*>(Wf)[i] = o.v;
  } else if (i < 32768 + 1536) {
    const int j = i - 32768;
    const int lane = j & 63;
    const int wt = (j >> 6) & 3;
    const int ks = j >> 8;
    const int n = 16 * wt + (lane & 15);
    const int kb = ks * 32 + (lane >> 4) * 8;
    union { short s[8]; bf16x8 v; } o;
#pragma unroll
    for (int jj = 0; jj < 8; ++jj)
      o.s[jj] = f2bf(W1[(size_t)(kb + jj) * 64 + n]);
    reinterpret_cast<bf16x8*>(W1f)[j] = o.v;
  } else if (i < 32768 + 1536 + 1024) {
    const int j = i - 32768 - 1536;
    const int lane = j & 63;
    const int wt = (j >> 6) & 3;
    const int ks = j >> 8;             // 0..3 over K=128
    const int n = 16 * wt + (lane & 15);
    const int kb = ks * 32 + (lane >> 4) * 8;
    union { short s[8]; bf16x8 v; } o;
#pragma unroll
    for (int jj = 0; jj < 8; ++jj)
      o.s[jj] = f2bf(Wc[(size_t)(kb + jj) * 64 + n]);
    reinterpret_cast<bf16x8*>(Wcf)[j] = o.v;
  }
}

// ---------------- Kernel A: img GEMM — one-shot micro-tile + coalesced store repack ----------------
__global__ __launch_bounds__(256, 5)
void img_gemm_mfma(const float* __restrict__ img_in,
                   const short* __restrict__ Wf,
                   __half* __restrict__ pp) {
  __shared__ short wlds[8192];    // 16 KB W frags
  __shared__ float alds[4096];    // 16 KB A tile [64 rows][16 slots] XOR-swizzled; reused for repack
  const int t = threadIdx.x;
  const int wave = t >> 6, lane = t & 63;
  const int lr = lane & 15, lk = lane >> 4;
  const int kq = blockIdx.x & 31, rgb = blockIdx.x >> 5;
  const int r0 = rgb * 64;
  __half* pout = pp + (size_t)kq * BB * 64;

  const short* wsrc = Wf + (size_t)kq * 8192;
#pragma unroll
  for (int i = 0; i < 4; ++i) {
    int j = i * 256 + t;
    gl_lds16(wsrc + j * 8, wlds + j * 8);
  }
#pragma unroll
  for (int i = 0; i < 4; ++i) {
    int j = i * 256 + t;                 // granule: row j>>4, slot j&15
    int r = j >> 4, c = j & 15;
    int gc = (c ^ (r & 7)) * 4;          // pre-swizzled source col (floats)
    gl_lds16(img_in + (size_t)(r0 + r) * IMGK + kq * 64 + gc, alds + j * 4);
  }
  asm volatile("s_waitcnt vmcnt(0)" ::: "memory");
  __syncthreads();

  const int arow = wave * 16 + lr;
  const int rx = arow & 7;
  float4 Af[2][2];
#pragma unroll
  for (int ks = 0; ks < 2; ++ks) {
    const int s0 = ks * 8 + lk * 2;
    Af[ks][0] = *reinterpret_cast<const float4*>(alds + arow * 64 + (s0 ^ rx) * 4);
    Af[ks][1] = *reinterpret_cast<const float4*>(alds + arow * 64 + ((s0 + 1) ^ rx) * 4);
  }
  const bf16x8* wp = reinterpret_cast<const bf16x8*>(wlds);
  f32x4 aHH[4], aER[4];
#pragma unroll
  for (int tt = 0; tt < 4; ++tt) {
    aHH[tt] = (f32x4){0.f, 0.f, 0.f, 0.f};
    aER[tt] = (f32x4){0.f, 0.f, 0.f, 0.f};
  }
#pragma unroll
  for (int ks = 0; ks < 2; ++ks) {
    float4 va = Af[ks][0], vb = Af[ks][1];
    union { unsigned u[4]; bf16x8 v; } hi, lo;
    hi.u[0] = pack_hi(va.x, va.y);
    hi.u[1] = pack_hi(va.z, va.w);
    hi.u[2] = pack_hi(vb.x, vb.y);
    hi.u[3] = pack_hi(vb.z, vb.w);
    lo.u[0] = pack_hi(va.x - trunc_bf(va.x), va.y - trunc_bf(va.y));
    lo.u[1] = pack_hi(va.z - trunc_bf(va.z), va.w - trunc_bf(va.w));
    lo.u[2] = pack_hi(vb.x - trunc_bf(vb.x), vb.y - trunc_bf(vb.y));
    lo.u[3] = pack_hi(vb.z - trunc_bf(vb.z), vb.w - trunc_bf(vb.w));
#pragma unroll
    for (int tt = 0; tt < 4; ++tt) {
      bf16x8 wh = wp[((ks * 4 + tt) * 2 + 0) * 64 + lane];
      bf16x8 wl = wp[((ks * 4 + tt) * 2 + 1) * 64 + lane];
      aHH[tt] = __builtin_amdgcn_mfma_f32_16x16x32_bf16(hi.v, wh, aHH[tt], 0, 0, 0);
      aER[tt] = __builtin_amdgcn_mfma_f32_16x16x32_bf16(hi.v, wl, aER[tt], 0, 0, 0);
      aER[tt] = __builtin_amdgcn_mfma_f32_16x16x32_bf16(lo.v, wh, aER[tt], 0, 0, 0);
    }
  }
  // wave-private repack through alds (rows wave*16..+15 both phases -> no barrier needed)
#pragma unroll
  for (int tt = 0; tt < 4; ++tt)
#pragma unroll
    for (int r = 0; r < 4; ++r)
      alds[(size_t)(wave * 16 + 4 * lk + r) * 64 + 16 * tt + lr] = aHH[tt][r] + aER[tt][r];
  asm volatile("s_waitcnt lgkmcnt(0)" ::: "memory");
  {
    const int row_l = lane >> 2, colq = (lane & 3) * 16;
    const float* src = alds + (size_t)(wave * 16 + row_l) * 64 + colq;
    union { __half h[8]; int4 v; } o1, o2;
#pragma unroll
    for (int j = 0; j < 8; ++j) {
      o1.h[j] = __float2half(src[j]);
      o2.h[j] = __float2half(src[8 + j]);
    }
    __half* dst = pout + (size_t)(r0 + wave * 16 + row_l) * 64 + colq;
    *reinterpret_cast<int4*>(dst) = o1.v;
    *reinterpret_cast<int4*>(dst + 8) = o2.v;
  }
}

// ---------------- mid: fused combine+attention+scores — 2 batches/wave, interleaved ILP ----------------
// 4 waves/block (256 thr), 2 batches/wave (slot = wave*2+p), grid BB/8.
// Two independent dependency chains per wave share each fence -> latency overlap.
__global__ __launch_bounds__(256, 3)
void mid_kernel(const int* __restrict__ user_input,
                const int* __restrict__ item_input,
                const int* __restrict__ ingre_input,
                const int* __restrict__ ingre_num,
                const float* __restrict__ user_emb,
                const float* __restrict__ item_emb,
                const float* __restrict__ ingre_emb,
                const __half* __restrict__ pp,
                const float* __restrict__ Wb, const float* __restrict__ bimg,
                const short* __restrict__ W1f,   // [6][4][64][8] bf16
                const float* __restrict__ Wib, const float* __restrict__ bai,
                const float* __restrict__ v,
                const short* __restrict__ Wcf,   // [4][4][64][8] bf16
                const float* __restrict__ Wcb, const float* __restrict__ bac,
                const float* __restrict__ vc,
                float* __restrict__ ws_img,
                float* __restrict__ ws_ia,
                float* __restrict__ ws_flat) {
  __shared__ short wflds[12288];        // 24 KB
  __shared__ short qe_s[8][20][72];     // 22.5 KB  (slot-major)
  __shared__ short ui_s[8][256];        // 4 KB
  __shared__ float sc_s[8][32];         // 1 KB
  const int t = threadIdx.x;
  const int wave = t >> 6, lane = t & 63;
  const int lr = lane & 15, lk = lane >> 4;
  const int b0 = blockIdx.x * 8 + wave * 2;

  for (int i = t; i < 1536; i += 256)
    reinterpret_cast<bf16x8*>(wflds)[i] = reinterpret_cast<const bf16x8*>(W1f)[i];

  // ---- phase A: gathers + pp sums for BOTH batches (interleaved issue) ----
  float qv[2][NN];
#pragma unroll
  for (int n = 0; n < NN; ++n)
#pragma unroll
    for (int p = 0; p < 2; ++p) {
      const int gi = ingre_input[(b0 + p) * NN + n];
      qv[p][n] = ingre_emb[(size_t)gi * 64 + lane];
    }
  __half hs[2];
#pragma unroll
  for (int p = 0; p < 2; ++p)
    hs[p] = pp[(size_t)(b0 + p) * 64 + lane];
#pragma unroll
  for (int kq = 1; kq < 32; ++kq)
#pragma unroll
    for (int p = 0; p < 2; ++p)
      hs[p] = __hadd(hs[p], pp[(size_t)kq * BB * 64 + (size_t)(b0 + p) * 64 + lane]);
  float sImg[2], ueV[2], ieV[2];
  int numN[2];
#pragma unroll
  for (int p = 0; p < 2; ++p) {
    sImg[p] = Wb[lane] + bimg[lane] + __half2float(hs[p]);
    const int u = user_input[b0 + p];
    const int it = item_input[b0 + p];
    ueV[p] = user_emb[(size_t)u * 64 + lane];
    ieV[p] = item_emb[(size_t)it * 64 + lane];
    numN[p] = ingre_num[b0 + p];
    ws_img[(size_t)(b0 + p) * 64 + lane] = sImg[p];
  }
  float vv[4], biasw[4];
#pragma unroll
  for (int wt = 0; wt < 4; ++wt) {
    vv[wt] = v[16 * wt + lr];
    biasw[wt] = Wib[16 * wt + lr] + bai[16 * wt + lr];
  }
  const float bbc = Wcb[lane] + bac[lane];
  const float vcl = vc[lane];

#pragma unroll
  for (int p = 0; p < 2; ++p) {
    const int sl = wave * 2 + p;
#pragma unroll
    for (int n = 0; n < NN; ++n) qe_s[sl][n][lane] = f2bf_t(qv[p][n]);
    ui_s[sl][lane] = f2bf_t(ueV[p]);
    ui_s[sl][64 + lane] = f2bf_t(sImg[p]);
    ui_s[sl][128 + lane] = f2bf_t(ieV[p]);
  }
  __syncthreads();

  // ---- phase B: attention MFMA for both batches ----
  const int r1 = (16 + lr < NN) ? 16 + lr : 0;
  bf16x8 aq0[2][2], aq1[2][2], au[2][4];
#pragma unroll
  for (int p = 0; p < 2; ++p) {
    const int sl = wave * 2 + p;
#pragma unroll
    for (int ks = 0; ks < 2; ++ks) {
      aq0[p][ks] = *reinterpret_cast<const bf16x8*>(&qe_s[sl][lr][ks * 32 + lk * 8]);
      aq1[p][ks] = *reinterpret_cast<const bf16x8*>(&qe_s[sl][r1][ks * 32 + lk * 8]);
    }
#pragma unroll
    for (int ks = 0; ks < 4; ++ks)
      au[p][ks] = *reinterpret_cast<const bf16x8*>(&ui_s[sl][ks * 32 + lk * 8]);
  }
  const bf16x8* wp = reinterpret_cast<const bf16x8*>(wflds);
  f32x4 accq[2][2][4], accb[2][4];
#pragma unroll
  for (int p = 0; p < 2; ++p)
#pragma unroll
    for (int wt = 0; wt < 4; ++wt) {
      accq[p][0][wt] = (f32x4){0.f, 0.f, 0.f, 0.f};
      accq[p][1][wt] = (f32x4){0.f, 0.f, 0.f, 0.f};
      accb[p][wt] = (f32x4){0.f, 0.f, 0.f, 0.f};
    }
#pragma unroll
  for (int ks = 0; ks < 2; ++ks)
#pragma unroll
    for (int wt = 0; wt < 4; ++wt) {
      bf16x8 w = wp[(ks * 4 + wt) * 64 + lane];
#pragma unroll
      for (int p = 0; p < 2; ++p) {
        accq[p][0][wt] = __builtin_amdgcn_mfma_f32_16x16x32_bf16(aq0[p][ks], w, accq[p][0][wt], 0, 0, 0);
        accq[p][1][wt] = __builtin_amdgcn_mfma_f32_16x16x32_bf16(aq1[p][ks], w, accq[p][1][wt], 0, 0, 0);
      }
    }
#pragma unroll
  for (int ks = 2; ks < 6; ++ks)
#pragma unroll
    for (int wt = 0; wt < 4; ++wt) {
      bf16x8 w = wp[(ks * 4 + wt) * 64 + lane];
#pragma unroll
      for (int p = 0; p < 2; ++p)
        accb[p][wt] = __builtin_amdgcn_mfma_f32_16x16x32_bf16(au[p][ks - 2], w, accb[p][wt], 0, 0, 0);
    }
  float sp[2][2][4];
#pragma unroll
  for (int p = 0; p < 2; ++p)
#pragma unroll
    for (int nt = 0; nt < 2; ++nt)
#pragma unroll
      for (int r = 0; r < 4; ++r) {
        float sv = 0.f;
#pragma unroll
        for (int wt = 0; wt < 4; ++wt) {
          float x = accq[p][nt][wt][r] + accb[p][wt][0] + biasw[wt];
          sv = fmaf(fast_tanh(x), vv[wt], sv);
        }
        sp[p][nt][r] = sv;
      }
#pragma unroll
  for (int off = 1; off < 16; off <<= 1)
#pragma unroll
    for (int p = 0; p < 2; ++p)
#pragma unroll
      for (int nt = 0; nt < 2; ++nt)
#pragma unroll
        for (int r = 0; r < 4; ++r) sp[p][nt][r] += __shfl_xor(sp[p][nt][r], off, 64);
  if (lr == 0) {
#pragma unroll
    for (int p = 0; p < 2; ++p)
#pragma unroll
      for (int r = 0; r < 4; ++r) {
        sc_s[wave * 2 + p][4 * lk + r] = sp[p][0][r];
        sc_s[wave * 2 + p][16 + 4 * lk + r] = sp[p][1][r];
      }
  }
  asm volatile("s_waitcnt lgkmcnt(0)" ::: "memory");

  // ---- phase C: softmax + ia for both batches ----
  float iaV[2];
#pragma unroll
  for (int p = 0; p < 2; ++p) {
    const int sl = wave * 2 + p;
    float scn[NN];
#pragma unroll
    for (int q = 0; q < 5; ++q) {
      float4 s4 = *reinterpret_cast<const float4*>(&sc_s[sl][4 * q]);
      scn[4 * q + 0] = s4.x; scn[4 * q + 1] = s4.y;
      scn[4 * q + 2] = s4.z; scn[4 * q + 3] = s4.w;
    }
    asm volatile("s_waitcnt lgkmcnt(0)" ::: "memory");
#pragma unroll
    for (int n = 0; n < NN; ++n) scn[n] = (n < numN[p]) ? scn[n] : -1e12f;
    float m01 = fmaxf(fmaxf(scn[0], scn[1]), scn[2]);
    float m02 = fmaxf(fmaxf(scn[3], scn[4]), scn[5]);
    float m03 = fmaxf(fmaxf(scn[6], scn[7]), scn[8]);
    float m04 = fmaxf(fmaxf(scn[9], scn[10]), scn[11]);
    float m05 = fmaxf(fmaxf(scn[12], scn[13]), scn[14]);
    float m06 = fmaxf(fmaxf(scn[15], scn[16]), scn[17]);
    float m07 = fmaxf(scn[18], scn[19]);
    float m = fmaxf(fmaxf(fmaxf(m01, m02), fmaxf(m03, m04)),
                    fmaxf(fmaxf(m05, m06), m07));
    float ssum = 0.f;
#pragma unroll
    for (int n = 0; n < NN; ++n) {
      scn[n] = __expf(scn[n] - m);
      ssum += scn[n];
    }
    const float inv = __fdividef(1.f, ssum);
    float ia = 0.f;
#pragma unroll
    for (int n = 0; n < NN; ++n) ia = fmaf(scn[n], qv[p][n], ia);
    ia *= inv;
    iaV[p] = ia;
    ws_ia[(size_t)(b0 + p) * 64 + lane] = ia;
    ui_s[sl][192 + lane] = f2bf_t(ia);
  }
  asm volatile("s_waitcnt lgkmcnt(0)" ::: "memory");

  // ---- phase D: component scores via MFMA for both batches ----
  const bf16x8 zerov = (bf16x8){0, 0, 0, 0, 0, 0, 0, 0};
  f32x4 accU[2][4], accY[2][4];
#pragma unroll
  for (int p = 0; p < 2; ++p)
#pragma unroll
    for (int wt = 0; wt < 4; ++wt) {
      accU[p][wt] = (f32x4){0.f, 0.f, 0.f, 0.f};
      accY[p][wt] = (f32x4){0.f, 0.f, 0.f, 0.f};
    }
  const int yoff = (lr == 0) ? 128 : (lr == 1) ? 192 : 64;
#pragma unroll
  for (int ks = 0; ks < 2; ++ks) {
#pragma unroll
    for (int wt = 0; wt < 4; ++wt) {
      bf16x8 wU = *reinterpret_cast<const bf16x8*>(Wcf + ((ks * 4 + wt) * 64 + lane) * 8);
      bf16x8 wY = *reinterpret_cast<const bf16x8*>(Wcf + (((ks + 2) * 4 + wt) * 64 + lane) * 8);
#pragma unroll
      for (int p = 0; p < 2; ++p) {
        const int sl = wave * 2 + p;
        bf16x8 aU = (lr == 0)
            ? *reinterpret_cast<const bf16x8*>(&ui_s[sl][ks * 32 + lk * 8]) : zerov;
        bf16x8 aY = (lr < 3)
            ? *reinterpret_cast<const bf16x8*>(&ui_s[sl][yoff + ks * 32 + lk * 8]) : zerov;
        accU[p][wt] = __builtin_amdgcn_mfma_f32_16x16x32_bf16(aU, wU, accU[p][wt], 0, 0, 0);
        accY[p][wt] = __builtin_amdgcn_mfma_f32_16x16x32_bf16(aY, wY, accY[p][wt], 0, 0, 0);
      }
    }
  }
#pragma unroll
  for (int p = 0; p < 2; ++p) {
    float* P4w = reinterpret_cast<float*>(&qe_s[wave * 2 + p][0][0]);
    if (lk == 0) {
#pragma unroll
      for (int wt = 0; wt < 4; ++wt) {
        P4w[0 * 64 + wt * 16 + lr] = accU[p][wt][0];
        P4w[1 * 64 + wt * 16 + lr] = accY[p][wt][0];
        P4w[2 * 64 + wt * 16 + lr] = accY[p][wt][1];
        P4w[3 * 64 + wt * 16 + lr] = accY[p][wt][2];
      }
    }
  }
  asm volatile("s_waitcnt lgkmcnt(0)" ::: "memory");
#pragma unroll
  for (int p = 0; p < 2; ++p) {
    const float* P4w = reinterpret_cast<const float*>(&qe_s[wave * 2 + p][0][0]);
    const float su = P4w[lane] + bbc;
    float sc3[3];
#pragma unroll
    for (int c = 0; c < 3; ++c) {
      float x = su + P4w[(1 + c) * 64 + lane];
      sc3[c] = waveReduceSum(fast_tanh(x) * vcl);
    }
    if (lane == 0) {
      ws_flat[b0 + p] = sc3[0];
      ws_flat[BB + b0 + p] = sc3[1];
      ws_flat[2 * BB + b0 + p] = sc3[2];
    }
  }
}

// ---------------- Kernel C: head. scores[i][j] = flat[3i+j] ----------------
__global__ __launch_bounds__(256, 3)
void head_kernel(const int* __restrict__ user_input,
                 const int* __restrict__ item_input,
                 const float* __restrict__ user_emb,
                 const float* __restrict__ item_emb,
                 const float* __restrict__ Wcat,   // [192][64]
                 const float* __restrict__ Wcatb,  // [64]
                 const float* __restrict__ bcat,   // [64]
                 const float* __restrict__ hw,     // [64]
                 const float* __restrict__ hb,     // [1]
                 const float* __restrict__ ws_img,
                 const float* __restrict__ ws_ia,
                 const float* __restrict__ ws_flat,
                 float* __restrict__ out) {
  __shared__ float Wlds[192 * 64];
  __shared__ float ue_s[4][64];
  __shared__ float itt_s[4][64];
  const int t = threadIdx.x;
  for (int i = t; i < 192 * 64 / 4; i += 256)
    reinterpret_cast<float4*>(Wlds)[i] = reinterpret_cast<const float4*>(Wcat)[i];
  __syncthreads();
  const int wave = t >> 6, lane = t & 63;
  const float bb = Wcatb[lane] + bcat[lane];
  const float hwl = hw[lane];
  const float hbv = hb[0];
  const int b0 = blockIdx.x * 16 + wave * 4;
#pragma unroll 1
  for (int bi = 0; bi < 4; ++bi) {
    const int b = b0 + bi;
    const float s0 = ws_flat[3 * b + 0];
    const float s1 = ws_flat[3 * b + 1];
    const float s2 = ws_flat[3 * b + 2];
    const float m = fmaxf(s0, fmaxf(s1, s2));
    const float e0 = __expf(s0 - m), e1 = __expf(s1 - m), e2 = __expf(s2 - m);
    const float inv = 1.0f / (e0 + e1 + e2);
    const int u = user_input[b];
    const int it = item_input[b];
    const float uev = user_emb[(size_t)u * 64 + lane];
    const float itt = (e0 * item_emb[(size_t)it * 64 + lane] +
                       e1 * ws_ia[(size_t)b * 64 + lane] +
                       e2 * ws_img[(size_t)b * 64 + lane]) * inv;
    ue_s[wave][lane] = uev;
    itt_s[wave][lane] = itt;
    asm volatile("s_waitcnt lgkmcnt(0)" ::: "memory");
    const float4* u4 = reinterpret_cast<const float4*>(&ue_s[wave][0]);
    const float4* i4 = reinterpret_cast<const float4*>(&itt_s[wave][0]);
    float h = bb;
#pragma unroll
    for (int d0 = 0; d0 < 16; ++d0) {
      float4 uu = u4[d0];
      float4 ii = i4[d0];
      int d = d0 * 4;
      h = fmaf(uu.x, Wlds[(d + 0) * 64 + lane], h);
      h = fmaf(ii.x, Wlds[(64 + d + 0) * 64 + lane], h);
      h = fmaf(uu.x * ii.x, Wlds[(128 + d + 0) * 64 + lane], h);
      h = fmaf(uu.y, Wlds[(d + 1) * 64 + lane], h);
      h = fmaf(ii.y, Wlds[(64 + d + 1) * 64 + lane], h);
      h = fmaf(uu.y * ii.y, Wlds[(128 + d + 1) * 64 + lane], h);
      h = fmaf(uu.z, Wlds[(d + 2) * 64 + lane], h);
      h = fmaf(ii.z, Wlds[(64 + d + 2) * 64 + lane], h);
      h = fmaf(uu.z * ii.z, Wlds[(128 + d + 2) * 64 + lane], h);
      h = fmaf(uu.w, Wlds[(d + 3) * 64 + lane], h);
      h = fmaf(ii.w, Wlds[(64 + d + 3) * 64 + lane], h);
      h = fmaf(uu.w * ii.w, Wlds[(128 + d + 3) * 64 + lane], h);
    }
    h = fmaxf(h, 0.f) * hwl;
    float o = waveReduceSum(h);
    if (lane == 0) out[b] = o + hbv;
    asm volatile("s_waitcnt lgkmcnt(0)" ::: "memory");
  }
}

extern "C" void kernel_launch(void* const* d_in, const int* in_sizes, int n_in,
                              void* d_out, int out_size, void* d_ws, size_t ws_size,
                              hipStream_t stream) {
  (void)in_sizes; (void)n_in; (void)out_size; (void)ws_size;
  const int* user_input = (const int*)d_in[0];
  const int* item_input = (const int*)d_in[1];
  const int* ingre_input = (const int*)d_in[2];
  const float* image_input = (const float*)d_in[3];
  const int* ingre_num = (const int*)d_in[4];
  const float* user_emb = (const float*)d_in[5];
  const float* item_emb = (const float*)d_in[6];
  const float* ingre_emb = (const float*)d_in[7];
  const float* W_image_w = (const float*)d_in[8];
  const float* W_image_b = (const float*)d_in[9];
  const float* b_image = (const float*)d_in[10];
  const float* W_concat_w = (const float*)d_in[11];
  const float* W_concat_b = (const float*)d_in[12];
  const float* b_concat = (const float*)d_in[13];
  const float* h_w = (const float*)d_in[14];
  const float* h_b = (const float*)d_in[15];
  const float* W_att_ingre_w = (const float*)d_in[16];
  const float* W_att_ingre_b = (const float*)d_in[17];
  const float* b_att_ingre = (const float*)d_in[18];
  const float* v = (const float*)d_in[19];
  const float* W_att_com_w = (const float*)d_in[20];
  const float* W_att_com_b = (const float*)d_in[21];
  const float* b_att_com = (const float*)d_in[22];
  const float* v_c = (const float*)d_in[23];

  float* ws = (float*)d_ws;
  float* ws_img = ws;                              // [B*64] f32
  float* ws_ia = ws + (size_t)BB * 64;             // [B*64] f32
  float* ws_flat = ws + (size_t)2 * BB * 64;       // [3B] f32
  short* Wf = (short*)(ws + (size_t)2 * BB * 64 + 3 * BB);      // [32*8192] bf16
  short* W1f = Wf + (size_t)32 * 8192;                          // [12288] bf16
  short* Wcf = W1f + 12288;                                     // [8192] bf16
  __half* pp = (__half*)(Wcf + 8192);              // [32][B*64] fp16 partials
  float* out = (float*)d_out;

  prep_kernel<<<(32768 + 1536 + 1024 + 255) / 256, 256, 0, stream>>>(
      W_image_w, W_att_ingre_w, W_att_com_w, Wf, W1f, Wcf);
  img_gemm_mfma<<<8192, 256, 0, stream>>>(image_input, Wf, pp);
  mid_kernel<<<BB / 8, 256, 0, stream>>>(user_input, item_input, ingre_input, ingre_num,
                                         user_emb, item_emb, ingre_emb, pp,
                                         W_image_b, b_image, W1f,
                                         W_att_ingre_b, b_att_ingre, v,
                                         Wcf, W_att_com_b, b_att_com, v_c,
                                         ws_img, ws_ia, ws_flat);
  head_kernel<<<BB / 16, 256, 0, stream>>>(user_input, item_input, user_emb, item_emb,
                                           W_concat_w, W_concat_b, b_concat, h_w, h_b,
                                           ws_img, ws_ia, ws_flat, out);
}

// Round 23
// 123.802 us; speedup vs baseline: 1.2372x; 1.2372x over previous
//
#include <hip/hip_runtime.h>
#include <hip/hip_fp16.h>

#define BB 16384
#define NN 20
#define DD 64
#define IMGK 2048

using bf16x8 = __attribute__((ext_vector_type(8))) short;
using f32x4  = __attribute__((ext_vector_type(4))) float;

typedef __attribute__((address_space(1))) const unsigned int GUint;
typedef __attribute__((address_space(3))) unsigned int LUint;
__device__ __forceinline__ void gl_lds16(const void* g, void* l) {
  __builtin_amdgcn_global_load_lds((GUint*)g, (LUint*)l, 16, 0, 0);
}

__device__ __forceinline__ float waveReduceSum(float x) {
#pragma unroll
  for (int off = 32; off > 0; off >>= 1) x += __shfl_xor(x, off, 64);
  return x;
}

__device__ __forceinline__ float fast_tanh(float x) {
  float e = __expf(2.f * x);
  return 1.f - __fdividef(2.f, e + 1.f);
}

__device__ __forceinline__ short f2bf(float f) {
  union { float f; unsigned u; } c; c.f = f;
  unsigned r = c.u + 0x7fffu + ((c.u >> 16) & 1u);
  return (short)(r >> 16);
}
__device__ __forceinline__ float bf2f(short s) {
  union { unsigned u; float f; } c; c.u = ((unsigned)(unsigned short)s) << 16;
  return c.f;
}
// truncation bf16 (1 VALU op) — used on non-critical paths
__device__ __forceinline__ short f2bf_t(float f) {
  return (short)(__float_as_uint(f) >> 16);
}

// truncation pack: top 16 bits of (a,b) -> one u32. Pure VALU.
__device__ __forceinline__ unsigned pack_hi(float a, float b) {
  unsigned ua = __float_as_uint(a), ub = __float_as_uint(b);
  return (ub & 0xffff0000u) | (ua >> 16);
}
__device__ __forceinline__ float trunc_bf(float a) {
  return __uint_as_float(__float_as_uint(a) & 0xffff0000u);
}

// ---------------- prep: Wf (img, frag-ordered hi/lo, kq=32) + W1f (K=192) + Wcf (K=128) ----------------
__global__ __launch_bounds__(256)
void prep_kernel(const float* __restrict__ Wimg, const float* __restrict__ W1,
                 const float* __restrict__ Wc,
                 short* __restrict__ Wf, short* __restrict__ W1f,
                 short* __restrict__ Wcf) {
  int i = blockIdx.x * 256 + threadIdx.x;
  if (i < 32768) {
    const int lane = i & 63;
    const int h = (i >> 6) & 1;
    const int tt = (i >> 7) & 3;
    const int ks = (i >> 9) & 1;
    const int kq = i >> 10;
    const int n = 16 * tt + (lane & 15);
    const int kb = kq * 64 + ks * 32 + (lane >> 4) * 8;
    union { short s[8]; bf16x8 v; } o;
#pragma unroll
    for (int j = 0; j < 8; ++j) {
      float f = Wimg[(size_t)(kb + j) * 64 + n];
      short hi = f2bf(f);
      o.s[j] = h == 0 ? hi : f2bf(f - bf2f(hi));
    }
    reinterpret_cast<bf16x8*>(Wf)[i] = o.v;
  } else if (i < 32768 + 1536) {
    const int j = i - 32768;
    const int lane = j & 63;
    const int wt = (j >> 6) & 3;
    const int ks = j >> 8;
    const int n = 16 * wt + (lane & 15);
    const int kb = ks * 32 + (lane >> 4) * 8;
    union { short s[8]; bf16x8 v; } o;
#pragma unroll
    for (int jj = 0; jj < 8; ++jj)
      o.s[jj] = f2bf(W1[(size_t)(kb + jj) * 64 + n]);
    reinterpret_cast<bf16x8*>(W1f)[j] = o.v;
  } else if (i < 32768 + 1536 + 1024) {
    const int j = i - 32768 - 1536;
    const int lane = j & 63;
    const int wt = (j >> 6) & 3;
    const int ks = j >> 8;             // 0..3 over K=128
    const int n = 16 * wt + (lane & 15);
    const int kb = ks * 32 + (lane >> 4) * 8;
    union { short s[8]; bf16x8 v; } o;
#pragma unroll
    for (int jj = 0; jj < 8; ++jj)
      o.s[jj] = f2bf(Wc[(size_t)(kb + jj) * 64 + n]);
    reinterpret_cast<bf16x8*>(Wcf)[j] = o.v;
  }
}

// ---------------- Kernel A: img GEMM — one-shot micro-tile + coalesced store repack ----------------
__global__ __launch_bounds__(256, 5)
void img_gemm_mfma(const float* __restrict__ img_in,
                   const short* __restrict__ Wf,
                   __half* __restrict__ pp) {
  __shared__ short wlds[8192];    // 16 KB W frags
  __shared__ float alds[4096];    // 16 KB A tile [64 rows][16 slots] XOR-swizzled; reused for repack
  const int t = threadIdx.x;
  const int wave = t >> 6, lane = t & 63;
  const int lr = lane & 15, lk = lane >> 4;
  const int kq = blockIdx.x & 31, rgb = blockIdx.x >> 5;
  const int r0 = rgb * 64;
  __half* pout = pp + (size_t)kq * BB * 64;

  const short* wsrc = Wf + (size_t)kq * 8192;
#pragma unroll
  for (int i = 0; i < 4; ++i) {
    int j = i * 256 + t;
    gl_lds16(wsrc + j * 8, wlds + j * 8);
  }
#pragma unroll
  for (int i = 0; i < 4; ++i) {
    int j = i * 256 + t;                 // granule: row j>>4, slot j&15
    int r = j >> 4, c = j & 15;
    int gc = (c ^ (r & 7)) * 4;          // pre-swizzled source col (floats)
    gl_lds16(img_in + (size_t)(r0 + r) * IMGK + kq * 64 + gc, alds + j * 4);
  }
  asm volatile("s_waitcnt vmcnt(0)" ::: "memory");
  __syncthreads();

  const int arow = wave * 16 + lr;
  const int rx = arow & 7;
  float4 Af[2][2];
#pragma unroll
  for (int ks = 0; ks < 2; ++ks) {
    const int s0 = ks * 8 + lk * 2;
    Af[ks][0] = *reinterpret_cast<const float4*>(alds + arow * 64 + (s0 ^ rx) * 4);
    Af[ks][1] = *reinterpret_cast<const float4*>(alds + arow * 64 + ((s0 + 1) ^ rx) * 4);
  }
  const bf16x8* wp = reinterpret_cast<const bf16x8*>(wlds);
  f32x4 aHH[4], aER[4];
#pragma unroll
  for (int tt = 0; tt < 4; ++tt) {
    aHH[tt] = (f32x4){0.f, 0.f, 0.f, 0.f};
    aER[tt] = (f32x4){0.f, 0.f, 0.f, 0.f};
  }
#pragma unroll
  for (int ks = 0; ks < 2; ++ks) {
    float4 va = Af[ks][0], vb = Af[ks][1];
    union { unsigned u[4]; bf16x8 v; } hi, lo;
    hi.u[0] = pack_hi(va.x, va.y);
    hi.u[1] = pack_hi(va.z, va.w);
    hi.u[2] = pack_hi(vb.x, vb.y);
    hi.u[3] = pack_hi(vb.z, vb.w);
    lo.u[0] = pack_hi(va.x - trunc_bf(va.x), va.y - trunc_bf(va.y));
    lo.u[1] = pack_hi(va.z - trunc_bf(va.z), va.w - trunc_bf(va.w));
    lo.u[2] = pack_hi(vb.x - trunc_bf(vb.x), vb.y - trunc_bf(vb.y));
    lo.u[3] = pack_hi(vb.z - trunc_bf(vb.z), vb.w - trunc_bf(vb.w));
#pragma unroll
    for (int tt = 0; tt < 4; ++tt) {
      bf16x8 wh = wp[((ks * 4 + tt) * 2 + 0) * 64 + lane];
      bf16x8 wl = wp[((ks * 4 + tt) * 2 + 1) * 64 + lane];
      aHH[tt] = __builtin_amdgcn_mfma_f32_16x16x32_bf16(hi.v, wh, aHH[tt], 0, 0, 0);
      aER[tt] = __builtin_amdgcn_mfma_f32_16x16x32_bf16(hi.v, wl, aER[tt], 0, 0, 0);
      aER[tt] = __builtin_amdgcn_mfma_f32_16x16x32_bf16(lo.v, wh, aER[tt], 0, 0, 0);
    }
  }
  // wave-private repack through alds (rows wave*16..+15 both phases -> no barrier needed)
#pragma unroll
  for (int tt = 0; tt < 4; ++tt)
#pragma unroll
    for (int r = 0; r < 4; ++r)
      alds[(size_t)(wave * 16 + 4 * lk + r) * 64 + 16 * tt + lr] = aHH[tt][r] + aER[tt][r];
  asm volatile("s_waitcnt lgkmcnt(0)" ::: "memory");
  {
    const int row_l = lane >> 2, colq = (lane & 3) * 16;
    const float* src = alds + (size_t)(wave * 16 + row_l) * 64 + colq;
    union { __half h[8]; int4 v; } o1, o2;
#pragma unroll
    for (int j = 0; j < 8; ++j) {
      o1.h[j] = __float2half(src[j]);
      o2.h[j] = __float2half(src[8 + j]);
    }
    __half* dst = pout + (size_t)(r0 + wave * 16 + row_l) * 64 + colq;
    *reinterpret_cast<int4*>(dst) = o1.v;
    *reinterpret_cast<int4*>(dst + 8) = o2.v;
  }
}

// ---------------- mid: combine(img) + ingre attention + component scores (fused) ----------------
// 8 waves/block (512 thr), 1 batch/wave, grid BB/8. VALU-diet version: truncation bf16
// packs, fp16 pp accumulation, max3 softmax tree. (Best-measured config, round 21.)
__global__ __launch_bounds__(512, 3)
void mid_kernel(const int* __restrict__ user_input,
                const int* __restrict__ item_input,
                const int* __restrict__ ingre_input,
                const int* __restrict__ ingre_num,
                const float* __restrict__ user_emb,
                const float* __restrict__ item_emb,
                const float* __restrict__ ingre_emb,
                const __half* __restrict__ pp,
                const float* __restrict__ Wb, const float* __restrict__ bimg,
                const short* __restrict__ W1f,   // [6][4][64][8] bf16
                const float* __restrict__ Wib, const float* __restrict__ bai,
                const float* __restrict__ v,
                const short* __restrict__ Wcf,   // [4][4][64][8] bf16
                const float* __restrict__ Wcb, const float* __restrict__ bac,
                const float* __restrict__ vc,
                float* __restrict__ ws_img,
                float* __restrict__ ws_ia,
                float* __restrict__ ws_flat) {
  __shared__ short wflds[12288];        // 24 KB
  __shared__ short qe_s[8][20][72];     // 22.5 KB (144B rows)
  __shared__ short ui_s[8][256];        // [ue|img|ie|ia] bf16, 4 KB
  __shared__ float sc_s[8][32];         // 1 KB
  const int t = threadIdx.x;
  const int wave = t >> 6, lane = t & 63;
  const int lr = lane & 15, lk = lane >> 4;
  const int b = blockIdx.x * 8 + wave;

  for (int i = t; i < 1536; i += 512)
    reinterpret_cast<bf16x8*>(wflds)[i] = reinterpret_cast<const bf16x8*>(W1f)[i];

  // per-lane gathers (latency overlaps staging)
  float qv[NN];
#pragma unroll
  for (int n = 0; n < NN; ++n) {
    const int gi = ingre_input[b * NN + n];
    qv[n] = ingre_emb[(size_t)gi * 64 + lane];
  }
  // pp sum in fp16 (1 v_add_f16 per slice)
  __half hsum = pp[(size_t)0 * BB * 64 + (size_t)b * 64 + lane];
#pragma unroll
  for (int kq = 1; kq < 32; ++kq)
    hsum = __hadd(hsum, pp[(size_t)kq * BB * 64 + (size_t)b * 64 + lane]);
  const float s = Wb[lane] + bimg[lane] + __half2float(hsum);
  const int u = user_input[b];
  const int it = item_input[b];
  const float ue = user_emb[(size_t)u * 64 + lane];
  const float iev = item_emb[(size_t)it * 64 + lane];
  ws_img[(size_t)b * 64 + lane] = s;
  float vv[4], biasw[4];
#pragma unroll
  for (int wt = 0; wt < 4; ++wt) {
    vv[wt] = v[16 * wt + lr];
    biasw[wt] = Wib[16 * wt + lr] + bai[16 * wt + lr];
  }
  const float bbc = Wcb[lane] + bac[lane];
  const float vcl = vc[lane];

  // truncation bf16 stores (1 op each)
#pragma unroll
  for (int n = 0; n < NN; ++n) qe_s[wave][n][lane] = f2bf_t(qv[n]);
  ui_s[wave][lane] = f2bf_t(ue);
  ui_s[wave][64 + lane] = f2bf_t(s);
  ui_s[wave][128 + lane] = f2bf_t(iev);
  __syncthreads();

  const int r1 = (16 + lr < NN) ? 16 + lr : 0;
  bf16x8 aq0[2], aq1[2], au[4];
#pragma unroll
  for (int ks = 0; ks < 2; ++ks) {
    aq0[ks] = *reinterpret_cast<const bf16x8*>(&qe_s[wave][lr][ks * 32 + lk * 8]);
    aq1[ks] = *reinterpret_cast<const bf16x8*>(&qe_s[wave][r1][ks * 32 + lk * 8]);
  }
#pragma unroll
  for (int ks = 0; ks < 4; ++ks)
    au[ks] = *reinterpret_cast<const bf16x8*>(&ui_s[wave][ks * 32 + lk * 8]);

  const bf16x8* wp = reinterpret_cast<const bf16x8*>(wflds);
  f32x4 accq[2][4], accb[4];
#pragma unroll
  for (int wt = 0; wt < 4; ++wt) {
    accq[0][wt] = (f32x4){0.f, 0.f, 0.f, 0.f};
    accq[1][wt] = (f32x4){0.f, 0.f, 0.f, 0.f};
    accb[wt] = (f32x4){0.f, 0.f, 0.f, 0.f};
  }
#pragma unroll
  for (int ks = 0; ks < 2; ++ks)
#pragma unroll
    for (int wt = 0; wt < 4; ++wt) {
      bf16x8 w = wp[(ks * 4 + wt) * 64 + lane];
      accq[0][wt] = __builtin_amdgcn_mfma_f32_16x16x32_bf16(aq0[ks], w, accq[0][wt], 0, 0, 0);
      accq[1][wt] = __builtin_amdgcn_mfma_f32_16x16x32_bf16(aq1[ks], w, accq[1][wt], 0, 0, 0);
    }
#pragma unroll
  for (int ks = 2; ks < 6; ++ks)
#pragma unroll
    for (int wt = 0; wt < 4; ++wt) {
      bf16x8 w = wp[(ks * 4 + wt) * 64 + lane];
      accb[wt] = __builtin_amdgcn_mfma_f32_16x16x32_bf16(au[ks - 2], w, accb[wt], 0, 0, 0);
    }
  float basew[4];
#pragma unroll
  for (int wt = 0; wt < 4; ++wt) basew[wt] = accb[wt][0] + biasw[wt];

  float sp[2][4];
#pragma unroll
  for (int nt = 0; nt < 2; ++nt)
#pragma unroll
    for (int r = 0; r < 4; ++r) {
      float sv = 0.f;
#pragma unroll
      for (int wt = 0; wt < 4; ++wt) {
        float x = accq[nt][wt][r] + basew[wt];
        sv = fmaf(fast_tanh(x), vv[wt], sv);
      }
      sp[nt][r] = sv;
    }
#pragma unroll
  for (int off = 1; off < 16; off <<= 1)
#pragma unroll
    for (int nt = 0; nt < 2; ++nt)
#pragma unroll
      for (int r = 0; r < 4; ++r) sp[nt][r] += __shfl_xor(sp[nt][r], off, 64);
  if (lr == 0) {
#pragma unroll
    for (int r = 0; r < 4; ++r) {
      sc_s[wave][4 * lk + r] = sp[0][r];
      sc_s[wave][16 + 4 * lk + r] = sp[1][r];
    }
  }
  asm volatile("s_waitcnt lgkmcnt(0)" ::: "memory");
  float scn[NN];
#pragma unroll
  for (int q = 0; q < 5; ++q) {
    float4 s4 = *reinterpret_cast<const float4*>(&sc_s[wave][4 * q]);
    scn[4 * q + 0] = s4.x; scn[4 * q + 1] = s4.y;
    scn[4 * q + 2] = s4.z; scn[4 * q + 3] = s4.w;
  }
  asm volatile("s_waitcnt lgkmcnt(0)" ::: "memory");
  const int num = ingre_num[b];
#pragma unroll
  for (int n = 0; n < NN; ++n) scn[n] = (n < num) ? scn[n] : -1e12f;
  float m01 = fmaxf(fmaxf(scn[0], scn[1]), scn[2]);
  float m02 = fmaxf(fmaxf(scn[3], scn[4]), scn[5]);
  float m03 = fmaxf(fmaxf(scn[6], scn[7]), scn[8]);
  float m04 = fmaxf(fmaxf(scn[9], scn[10]), scn[11]);
  float m05 = fmaxf(fmaxf(scn[12], scn[13]), scn[14]);
  float m06 = fmaxf(fmaxf(scn[15], scn[16]), scn[17]);
  float m07 = fmaxf(scn[18], scn[19]);
  float m = fmaxf(fmaxf(fmaxf(m01, m02), fmaxf(m03, m04)),
                  fmaxf(fmaxf(m05, m06), m07));
  float ssum = 0.f;
#pragma unroll
  for (int n = 0; n < NN; ++n) {
    scn[n] = __expf(scn[n] - m);
    ssum += scn[n];
  }
  const float inv = __fdividef(1.f, ssum);
  float ia = 0.f;
#pragma unroll
  for (int n = 0; n < NN; ++n) ia = fmaf(scn[n], qv[n], ia);
  ia *= inv;
  ws_ia[(size_t)b * 64 + lane] = ia;

  // ---- component scores via MFMA (P4 aliased into dead qe_s region) ----
  float* P4w = reinterpret_cast<float*>(&qe_s[wave][0][0]);
  ui_s[wave][192 + lane] = f2bf_t(ia);
  asm volatile("s_waitcnt lgkmcnt(0)" ::: "memory");
  const bf16x8 zerov = (bf16x8){0, 0, 0, 0, 0, 0, 0, 0};
  f32x4 accU[4], accY[4];
#pragma unroll
  for (int wt = 0; wt < 4; ++wt) {
    accU[wt] = (f32x4){0.f, 0.f, 0.f, 0.f};
    accY[wt] = (f32x4){0.f, 0.f, 0.f, 0.f};
  }
  const int yoff = (lr == 0) ? 128 : (lr == 1) ? 192 : 64;
#pragma unroll
  for (int ks = 0; ks < 2; ++ks) {
    bf16x8 aU = (lr == 0)
        ? *reinterpret_cast<const bf16x8*>(&ui_s[wave][ks * 32 + lk * 8]) : zerov;
    bf16x8 aY = (lr < 3)
        ? *reinterpret_cast<const bf16x8*>(&ui_s[wave][yoff + ks * 32 + lk * 8]) : zerov;
#pragma unroll
    for (int wt = 0; wt < 4; ++wt) {
      bf16x8 wU = *reinterpret_cast<const bf16x8*>(Wcf + ((ks * 4 + wt) * 64 + lane) * 8);
      bf16x8 wY = *reinterpret_cast<const bf16x8*>(Wcf + (((ks + 2) * 4 + wt) * 64 + lane) * 8);
      accU[wt] = __builtin_amdgcn_mfma_f32_16x16x32_bf16(aU, wU, accU[wt], 0, 0, 0);
      accY[wt] = __builtin_amdgcn_mfma_f32_16x16x32_bf16(aY, wY, accY[wt], 0, 0, 0);
    }
  }
  if (lk == 0) {
#pragma unroll
    for (int wt = 0; wt < 4; ++wt) {
      P4w[0 * 64 + wt * 16 + lr] = accU[wt][0];
      P4w[1 * 64 + wt * 16 + lr] = accY[wt][0];
      P4w[2 * 64 + wt * 16 + lr] = accY[wt][1];
      P4w[3 * 64 + wt * 16 + lr] = accY[wt][2];
    }
  }
  asm volatile("s_waitcnt lgkmcnt(0)" ::: "memory");
  const float su = P4w[lane] + bbc;
  float sc3[3];
#pragma unroll
  for (int c = 0; c < 3; ++c) {
    float x = su + P4w[(1 + c) * 64 + lane];
    sc3[c] = waveReduceSum(fast_tanh(x) * vcl);
  }
  if (lane == 0) {
    ws_flat[b] = sc3[0];
    ws_flat[BB + b] = sc3[1];
    ws_flat[2 * BB + b] = sc3[2];
  }
}

// ---------------- Kernel C: head. scores[i][j] = flat[3i+j] ----------------
__global__ __launch_bounds__(256, 3)
void head_kernel(const int* __restrict__ user_input,
                 const int* __restrict__ item_input,
                 const float* __restrict__ user_emb,
                 const float* __restrict__ item_emb,
                 const float* __restrict__ Wcat,   // [192][64]
                 const float* __restrict__ Wcatb,  // [64]
                 const float* __restrict__ bcat,   // [64]
                 const float* __restrict__ hw,     // [64]
                 const float* __restrict__ hb,     // [1]
                 const float* __restrict__ ws_img,
                 const float* __restrict__ ws_ia,
                 const float* __restrict__ ws_flat,
                 float* __restrict__ out) {
  __shared__ float Wlds[192 * 64];
  __shared__ float ue_s[4][64];
  __shared__ float itt_s[4][64];
  const int t = threadIdx.x;
  for (int i = t; i < 192 * 64 / 4; i += 256)
    reinterpret_cast<float4*>(Wlds)[i] = reinterpret_cast<const float4*>(Wcat)[i];
  __syncthreads();
  const int wave = t >> 6, lane = t & 63;
  const float bb = Wcatb[lane] + bcat[lane];
  const float hwl = hw[lane];
  const float hbv = hb[0];
  const int b0 = blockIdx.x * 16 + wave * 4;
#pragma unroll 1
  for (int bi = 0; bi < 4; ++bi) {
    const int b = b0 + bi;
    const float s0 = ws_flat[3 * b + 0];
    const float s1 = ws_flat[3 * b + 1];
    const float s2 = ws_flat[3 * b + 2];
    const float m = fmaxf(s0, fmaxf(s1, s2));
    const float e0 = __expf(s0 - m), e1 = __expf(s1 - m), e2 = __expf(s2 - m);
    const float inv = 1.0f / (e0 + e1 + e2);
    const int u = user_input[b];
    const int it = item_input[b];
    const float uev = user_emb[(size_t)u * 64 + lane];
    const float itt = (e0 * item_emb[(size_t)it * 64 + lane] +
                       e1 * ws_ia[(size_t)b * 64 + lane] +
                       e2 * ws_img[(size_t)b * 64 + lane]) * inv;
    ue_s[wave][lane] = uev;
    itt_s[wave][lane] = itt;
    asm volatile("s_waitcnt lgkmcnt(0)" ::: "memory");
    const float4* u4 = reinterpret_cast<const float4*>(&ue_s[wave][0]);
    const float4* i4 = reinterpret_cast<const float4*>(&itt_s[wave][0]);
    float h = bb;
#pragma unroll
    for (int d0 = 0; d0 < 16; ++d0) {
      float4 uu = u4[d0];
      float4 ii = i4[d0];
      int d = d0 * 4;
      h = fmaf(uu.x, Wlds[(d + 0) * 64 + lane], h);
      h = fmaf(ii.x, Wlds[(64 + d + 0) * 64 + lane], h);
      h = fmaf(uu.x * ii.x, Wlds[(128 + d + 0) * 64 + lane], h);
      h = fmaf(uu.y, Wlds[(d + 1) * 64 + lane], h);
      h = fmaf(ii.y, Wlds[(64 + d + 1) * 64 + lane], h);
      h = fmaf(uu.y * ii.y, Wlds[(128 + d + 1) * 64 + lane], h);
      h = fmaf(uu.z, Wlds[(d + 2) * 64 + lane], h);
      h = fmaf(ii.z, Wlds[(64 + d + 2) * 64 + lane], h);
      h = fmaf(uu.z * ii.z, Wlds[(128 + d + 2) * 64 + lane], h);
      h = fmaf(uu.w, Wlds[(d + 3) * 64 + lane], h);
      h = fmaf(ii.w, Wlds[(64 + d + 3) * 64 + lane], h);
      h = fmaf(uu.w * ii.w, Wlds[(128 + d + 3) * 64 + lane], h);
    }
    h = fmaxf(h, 0.f) * hwl;
    float o = waveReduceSum(h);
    if (lane == 0) out[b] = o + hbv;
    asm volatile("s_waitcnt lgkmcnt(0)" ::: "memory");
  }
}

extern "C" void kernel_launch(void* const* d_in, const int* in_sizes, int n_in,
                              void* d_out, int out_size, void* d_ws, size_t ws_size,
                              hipStream_t stream) {
  (void)in_sizes; (void)n_in; (void)out_size; (void)ws_size;
  const int* user_input = (const int*)d_in[0];
  const int* item_input = (const int*)d_in[1];
  const int* ingre_input = (const int*)d_in[2];
  const float* image_input = (const float*)d_in[3];
  const int* ingre_num = (const int*)d_in[4];
  const float* user_emb = (const float*)d_in[5];
  const float* item_emb = (const float*)d_in[6];
  const float* ingre_emb = (const float*)d_in[7];
  const float* W_image_w = (const float*)d_in[8];
  const float* W_image_b = (const float*)d_in[9];
  const float* b_image = (const float*)d_in[10];
  const float* W_concat_w = (const float*)d_in[11];
  const float* W_concat_b = (const float*)d_in[12];
  const float* b_concat = (const float*)d_in[13];
  const float* h_w = (const float*)d_in[14];
  const float* h_b = (const float*)d_in[15];
  const float* W_att_ingre_w = (const float*)d_in[16];
  const float* W_att_ingre_b = (const float*)d_in[17];
  const float* b_att_ingre = (const float*)d_in[18];
  const float* v = (const float*)d_in[19];
  const float* W_att_com_w = (const float*)d_in[20];
  const float* W_att_com_b = (const float*)d_in[21];
  const float* b_att_com = (const float*)d_in[22];
  const float* v_c = (const float*)d_in[23];

  float* ws = (float*)d_ws;
  float* ws_img = ws;                              // [B*64] f32
  float* ws_ia = ws + (size_t)BB * 64;             // [B*64] f32
  float* ws_flat = ws + (size_t)2 * BB * 64;       // [3B] f32
  short* Wf = (short*)(ws + (size_t)2 * BB * 64 + 3 * BB);      // [32*8192] bf16
  short* W1f = Wf + (size_t)32 * 8192;                          // [12288] bf16
  short* Wcf = W1f + 12288;                                     // [8192] bf16
  __half* pp = (__half*)(Wcf + 8192);              // [32][B*64] fp16 partials
  float* out = (float*)d_out;

  prep_kernel<<<(32768 + 1536 + 1024 + 255) / 256, 256, 0, stream>>>(
      W_image_w, W_att_ingre_w, W_att_com_w, Wf, W1f, Wcf);
  img_gemm_mfma<<<8192, 256, 0, stream>>>(image_input, Wf, pp);
  mid_kernel<<<BB / 8, 512, 0, stream>>>(user_input, item_input, ingre_input, ingre_num,
                                         user_emb, item_emb, ingre_emb, pp,
                                         W_image_b, b_image, W1f,
                                         W_att_ingre_b, b_att_ingre, v,
                                         Wcf, W_att_com_b, b_att_com, v_c,
                                         ws_img, ws_ia, ws_flat);
  head_kernel<<<BB / 16, 256, 0, stream>>>(user_input, item_input, user_emb, item_emb,
                                           W_concat_w, W_concat_b, b_concat, h_w, h_b,
                                           ws_img, ws_ia, ws_flat, out);
}